// Round 1
// baseline (917.816 us; speedup 1.0000x reference)
//
#include <hip/hip_runtime.h>

#define BB 32
#define SS 128
#define LL 4096
#define KK 129
#define NST 10

// ---------- constexpr twiddles: TW[j] = e^{-2*pi*i*j/128}, j in [0,64) ----------
constexpr double PI_D = 3.141592653589793238462643383279502884;
constexpr double red_sin(double x){ // |x| <= pi/2, Taylor to x^17
  double x2 = x*x, t = x, r = x;
  t *= -x2/6.0;   r += t;
  t *= -x2/20.0;  r += t;
  t *= -x2/42.0;  r += t;
  t *= -x2/72.0;  r += t;
  t *= -x2/110.0; r += t;
  t *= -x2/156.0; r += t;
  t *= -x2/210.0; r += t;
  t *= -x2/272.0; r += t;
  return r;
}
constexpr double csin_d(double x){
  while (x >  PI_D) x -= 2.0*PI_D;
  while (x < -PI_D) x += 2.0*PI_D;
  if (x >  PI_D*0.5)      x =  PI_D - x;
  else if (x < -PI_D*0.5) x = -PI_D - x;
  return red_sin(x);
}
constexpr double ccos_d(double x){ return csin_d(x + PI_D*0.5); }
struct TWT { float c[64]; float s[64]; };
constexpr TWT make_tw(){
  TWT t{};
  for (int j = 0; j < 64; j++){
    double a = -2.0*PI_D*(double)j/128.0;
    t.c[j] = (float)ccos_d(a);
    t.s[j] = (float)csin_d(a);
  }
  return t;
}
constexpr TWT TW = make_tw();

// ---------- matched filter: out[row, l] = sum_k x[row, l+k-64] * conj(kernel[k]) ----------
__global__ __launch_bounds__(256) void mf_kernel(const float* __restrict__ xr,
                                                 const float* __restrict__ xi,
                                                 const float* __restrict__ kr,
                                                 const float* __restrict__ ki,
                                                 float2* __restrict__ out)
{
  const int row = blockIdx.x;            // b*S + s
  const int t = threadIdx.x;             // 256
  __shared__ float2 xs[LL + KK - 1];     // 4224
  __shared__ float2 ks[KK];
  const float* xrr = xr + (size_t)row*LL;
  const float* xir = xi + (size_t)row*LL;
  for (int i = t; i < LL + KK - 1; i += 256){
    int l = i - 64;
    float a = (l >= 0 && l < LL) ? xrr[l] : 0.0f;
    float c = (l >= 0 && l < LL) ? xir[l] : 0.0f;
    xs[i] = make_float2(a, c);
  }
  if (t < KK) ks[t] = make_float2(kr[t], ki[t]);
  __syncthreads();

  float2 acc[16];
  #pragma unroll
  for (int j = 0; j < 16; j++) acc[j] = make_float2(0.0f, 0.0f);

  for (int k = 0; k < KK; k++){
    const float2 w = ks[k];   // uniform -> LDS broadcast
    #pragma unroll
    for (int j = 0; j < 16; j++){
      float2 xv = xs[t + j*256 + k];
      acc[j].x += xv.x*w.x + xv.y*w.y;   // re:  xr*kr + xi*ki
      acc[j].y += xv.y*w.x - xv.x*w.y;   // im:  xi*kr - xr*ki
    }
  }
  float2* orow = out + (size_t)row*LL;
  #pragma unroll
  for (int j = 0; j < 16; j++) orow[t + j*256] = acc[j];
}

// ---------- init: w_mag=1, w_phase=w_phase_init, c = exp(-i*atan(wp)), zero slots/out ----------
__global__ void init_kernel(const float* __restrict__ wpi,
                            float* __restrict__ w_mag, float* __restrict__ w_phase,
                            float2* __restrict__ cvec, unsigned long long* __restrict__ slots,
                            float* __restrict__ out)
{
  const int i = blockIdx.x*256 + threadIdx.x;
  if (i < BB*SS){
    float wp = wpi[i];
    w_mag[i] = 1.0f;
    w_phase[i] = wp;
    float phi = atanf(wp);
    float s, c;
    sincosf(phi, &s, &c);
    cvec[i] = make_float2(c, -s);      // m = 1 exactly (softmax of equal values)
  }
  if (i < BB) slots[i] = 0ull;
  if (i == 0) out[0] = 0.0f;
}

// ---------- FFT-64 DIF stage (in-register, compile-time twiddles) ----------
template<int SPAN>
__device__ __forceinline__ void fstage(float2* v){
  #pragma unroll
  for (int base = 0; base < 64; base += 2*SPAN){
    #pragma unroll
    for (int j = 0; j < SPAN; j++){
      const int i0 = base + j, i1 = base + j + SPAN;
      float ax = v[i0].x, ay = v[i0].y, bx = v[i1].x, by = v[i1].y;
      float sx = ax - bx, sy = ay - by;
      v[i0].x = ax + bx; v[i0].y = ay + by;
      const int tj = j * (64 / SPAN);   // W_{2*SPAN}^j = TW[tj]
      if (tj == 0){
        v[i1].x = sx; v[i1].y = sy;
      } else if (tj == 32){             // W = -i
        v[i1].x = sy; v[i1].y = -sx;
      } else {
        const float wr = TW.c[tj], wi = TW.s[tj];
        v[i1].x = sx*wr - sy*wi;
        v[i1].y = sy*wr + sx*wi;
      }
    }
  }
}

// ---------- scan: per (b,l) compute max_s |FFT_128(c .* x[:,l])|^2, argmax over l per b ----------
__global__ __launch_bounds__(256) void scan_kernel(const float2* __restrict__ xmf,
                                                   const float2* __restrict__ cvec,
                                                   unsigned long long* __restrict__ slots)
{
  const int b = blockIdx.y;
  const int tid = threadIdx.x;
  const int p = tid >> 1, r = tid & 1;     // 2 lanes per FFT; partner = lane^1
  const int l = blockIdx.x*128 + p;
  __shared__ float2 csh[SS];
  __shared__ unsigned long long red[256];
  if (tid < SS) csh[tid] = cvec[b*SS + tid];
  __syncthreads();

  const float2* xb = xmf + ((size_t)(b*SS + r*64))*LL + l;
  float2 v[64];
  #pragma unroll
  for (int j = 0; j < 64; j++){
    float2 x = xb[(size_t)j*LL];
    float2 c = csh[r*64 + j];
    v[j].x = c.x*x.x - c.y*x.y;
    v[j].y = c.x*x.y + c.y*x.x;
  }
  // DIF stage 1 across the lane pair: r=0 -> a+b (even bins), r=1 -> (a-b)*W128^j (odd bins)
  const float sgn = r ? -1.0f : 1.0f;
  #pragma unroll
  for (int j = 0; j < 64; j++){
    float px = __shfl_xor(v[j].x, 1);
    float py = __shfl_xor(v[j].y, 1);
    float ux = fmaf(sgn, v[j].x, px);
    float uy = fmaf(sgn, v[j].y, py);
    float wr = r ? TW.c[j] : 1.0f;
    float wi = r ? TW.s[j] : 0.0f;
    v[j].x = ux*wr - uy*wi;
    v[j].y = uy*wr + ux*wi;
  }
  // local FFT-64 (bit-reversed output order; irrelevant for max)
  fstage<32>(v); fstage<16>(v); fstage<8>(v);
  fstage<4>(v);  fstage<2>(v);  fstage<1>(v);

  float mm = 0.0f;
  #pragma unroll
  for (int j = 0; j < 64; j++) mm = fmaxf(mm, v[j].x*v[j].x + v[j].y*v[j].y);
  mm = fmaxf(mm, __shfl_xor(mm, 1));    // combine even/odd bins of the pair

  unsigned long long pk = ((unsigned long long)__float_as_uint(mm) << 32) | (unsigned int)l;
  red[tid] = pk;
  __syncthreads();
  #pragma unroll
  for (int st = 128; st > 0; st >>= 1){
    if (tid < st){ unsigned long long o = red[tid + st]; if (o > red[tid]) red[tid] = o; }
    __syncthreads();
  }
  if (tid == 0) atomicMax(slots + b, red[0]);
}

// ---------- block reductions (128 threads) ----------
__device__ __forceinline__ float bsum(float v, float* red, int t){
  __syncthreads();
  red[t] = v; __syncthreads();
  #pragma unroll
  for (int st = 64; st > 0; st >>= 1){
    if (t < st) red[t] += red[t + st];
    __syncthreads();
  }
  return red[0];
}
__device__ __forceinline__ float bmax(float v, float* red, int t){
  __syncthreads();
  red[t] = v; __syncthreads();
  #pragma unroll
  for (int st = 64; st > 0; st >>= 1){
    if (t < st) red[t] = fmaxf(red[t], red[t + st]);
    __syncthreads();
  }
  return red[0];
}

// ---------- per-step gradient + update (or final SNR); one block per b, 128 threads ----------
__global__ __launch_bounds__(128) void step_kernel(const float2* __restrict__ xmf,
                                                   float* __restrict__ w_mag,
                                                   float* __restrict__ w_phase,
                                                   float2* __restrict__ cvec,
                                                   unsigned long long* __restrict__ slots,
                                                   const float* __restrict__ lsm,
                                                   const float* __restrict__ lsp,
                                                   int stepi, int isFinal,
                                                   float* __restrict__ out)
{
  const int b = blockIdx.x, t = threadIdx.x;   // t = s (phase A) = k (phase B)
  __shared__ float red[128];
  __shared__ float2 ysh[128];
  __shared__ float twc[128], tws[128];         // e^{-2 pi i j/128} = (twc, tws)
  __shared__ float speak;
  __shared__ int sidx;

  const int rbin = (int)(slots[b] & 0xffffffffull);
  float wm = w_mag[b*SS + t];
  float wp = w_phase[b*SS + t];
  const float2 xc = xmf[((size_t)(b*SS + t))*LL + rbin];
  float phi = atanf(wp);
  float sph, cph;
  sincosf(phi, &sph, &cph);
  {
    float sv, cv;
    sincosf((float)(2.0*PI_D/128.0) * (float)t, &sv, &cv);
    twc[t] = cv; tws[t] = -sv;
  }
  // softmax -> m = S * softmax(w_mag)
  float mx = bmax(wm, red, t);
  float ex = expf(wm - mx);
  float sm = bsum(ex, red, t);
  float m = 128.0f * ex / sm;
  float cre = m*cph, cim = -m*sph;
  ysh[t] = make_float2(cre*xc.x - cim*xc.y, cre*xc.y + cim*xc.x);
  __syncthreads();

  // F[k] = sum_s e^{-2 pi i k s/128} y[s]   (thread t = k)
  float Fr = 0.0f, Fi = 0.0f;
  #pragma unroll 8
  for (int s2 = 0; s2 < 128; s2++){
    int id = (t*s2) & 127;
    float wr = twc[id], wi = tws[id];
    float2 ys = ysh[s2];
    Fr += wr*ys.x - wi*ys.y;
    Fi += wr*ys.y + wi*ys.x;
  }
  const int u = (t + 64) & 127;        // fftshifted index this thread owns
  float colu = Fr*Fr + Fi*Fi;

  float total = bsum(colu, red, t);
  float zre = bsum(colu * twc[u], red, t);        // e^{+i*2pi*u/128} = (twc[u], -tws[u])
  float zim = bsum(colu * (-tws[u]), red, t);
  if (t == 0){
    float ang = atan2f(zim, zre);
    float pidx = ang * (128.0f/(2.0f*(float)PI_D));
    float rr = rintf(pidx);                       // round half-to-even == jnp.round
    sidx = ((int)rr) & 127;                       // mod 128 (pow2, handles negatives)
  }
  __syncthreads();
  const int idx = sidx;
  if (u == idx) speak = colu;
  __syncthreads();
  const float peak = speak;
  const float noise = (total - peak) * (1.0f/127.0f);

  if (isFinal){
    if (t == 0) atomicAdd(out, 10.0f*(log10f(peak) - log10f(noise)) * (1.0f/(float)BB));
    return;
  }

  // d snr / d col[u]
  constexpr float C10 = 4.342944819032518f;       // 10/ln(10)
  float g = (u == idx) ? (C10/peak) : (-C10/(127.0f*noise));
  // G[k] = 2*gF[k]*F[k];  gF[k] = g_col[(k+64)&127] = this thread's own g
  __syncthreads();
  ysh[t] = make_float2(2.0f*g*Fr, 2.0f*g*Fi);
  __syncthreads();

  // T[s] = sum_k e^{+2 pi i k s/128} G[k]   (thread t = s)
  float Tr = 0.0f, Ti = 0.0f;
  #pragma unroll 8
  for (int k = 0; k < 128; k++){
    int id = (t*k) & 127;
    float wr = twc[id], wi = -tws[id];
    float2 G = ysh[k];
    Tr += wr*G.x - wi*G.y;
    Ti += wr*G.y + wi*G.x;
  }
  // H = conj(x_col) * T
  float Hr = xc.x*Tr + xc.y*Ti;
  float Hi = xc.x*Ti - xc.y*Tr;
  float dm   = Hr*cph - Hi*sph;                   // dL/dm   = Re(H e^{i phi})
  float dphi = -m*(Hr*sph + Hi*cph);              // dL/dphi = -m Im(H e^{i phi})
  // softmax backward: gw = m*(dm - (1/S) sum_t m_t dm_t)
  float S1 = bsum(m*dm, red, t);
  float gwm = m*(dm - S1*(1.0f/128.0f));
  float gwp = dphi / (1.0f + wp*wp);              // d atan

  constexpr float LN10 = 2.302585092994046f;
  float lrm = expf(lsm[t*NST + stepi] * LN10);
  float lrp = expf(lsp[t*NST + stepi] * LN10);
  wm += lrm*gwm;
  wp += lrp*gwp;
  w_mag[b*SS + t] = wm;
  w_phase[b*SS + t] = wp;

  // c for the next scan
  float mx2 = bmax(wm, red, t);
  float ex2 = expf(wm - mx2);
  float sm2 = bsum(ex2, red, t);
  float m2 = 128.0f * ex2 / sm2;
  float phi2 = atanf(wp);
  float s2v, c2v;
  sincosf(phi2, &s2v, &c2v);
  cvec[b*SS + t] = make_float2(m2*c2v, -m2*s2v);
  if (t == 0) slots[b] = 0ull;                    // reset argmax slot for next scan
}

extern "C" void kernel_launch(void* const* d_in, const int* in_sizes, int n_in,
                              void* d_out, int out_size, void* d_ws, size_t ws_size,
                              hipStream_t stream)
{
  const float* x_re = (const float*)d_in[0];
  const float* x_im = (const float*)d_in[1];
  const float* k_re = (const float*)d_in[2];
  const float* k_im = (const float*)d_in[3];
  const float* lsm  = (const float*)d_in[4];
  const float* lsp  = (const float*)d_in[5];
  const float* wpi  = (const float*)d_in[6];
  float* out = (float*)d_out;

  char* ws = (char*)d_ws;
  size_t off = 0;
  float2* xmf = (float2*)(ws + off);                 off += (size_t)BB*SS*LL*sizeof(float2);
  unsigned long long* slots = (unsigned long long*)(ws + off); off += 256;
  float* w_mag   = (float*)(ws + off);               off += (size_t)BB*SS*4;
  float* w_phase = (float*)(ws + off);               off += (size_t)BB*SS*4;
  float2* cvec   = (float2*)(ws + off);              off += (size_t)BB*SS*8;
  if (ws_size < off) return;   // insufficient scratch -> fail visibly

  mf_kernel<<<BB*SS, 256, 0, stream>>>(x_re, x_im, k_re, k_im, xmf);
  init_kernel<<<(BB*SS + 255)/256, 256, 0, stream>>>(wpi, w_mag, w_phase, cvec, slots, out);
  for (int i = 0; i < NST; i++){
    scan_kernel<<<dim3(LL/128, BB), 256, 0, stream>>>(xmf, cvec, slots);
    step_kernel<<<BB, 128, 0, stream>>>(xmf, w_mag, w_phase, cvec, slots, lsm, lsp, i, 0, out);
  }
  scan_kernel<<<dim3(LL/128, BB), 256, 0, stream>>>(xmf, cvec, slots);
  step_kernel<<<BB, 128, 0, stream>>>(xmf, w_mag, w_phase, cvec, slots, lsm, lsp, 0, 1, out);
}